// Round 1
// baseline (305.105 us; speedup 1.0000x reference)
//
#include <hip/hip_runtime.h>
#include <cstdint>
#include <cstddef>

typedef __bf16 bf16;
typedef __bf16 bf16x4 __attribute__((ext_vector_type(4)));
typedef __bf16 bf16x8 __attribute__((ext_vector_type(8)));
typedef float floatx4 __attribute__((ext_vector_type(4)));

#define NB 4096   // batch
#define ND 2048   // feature dim
#define NCLS 64   // classes

// ---------------------------------------------------------------- staging ---
__device__ __forceinline__ void stage16(const void* g, void* l) {
  // async global -> LDS, 16B per lane, LDS dest = wave-uniform base + lane*16
  __builtin_amdgcn_global_load_lds(
      (__attribute__((address_space(1))) unsigned int*)g,
      (__attribute__((address_space(3))) unsigned int*)l, 16, 0, 0);
}

// ------------------------------------------------------------- GEMM core ----
// C[M][N] = A[M][K] * B[N][K]^T, bf16 inputs, fp32 accum.
// Block: 256 thr = 4 waves (2x2), tile 128x128, BK=32.
// Wave (wm,wn) owns a 64x64 quadrant as 4x4 grid of 16x16x32 MFMA tiles.
__device__ __forceinline__ void gemm_core(const bf16* __restrict__ A,
                                          const bf16* __restrict__ Bm, int K,
                                          int m0, int n0, bf16* As, bf16* Bs,
                                          floatx4 acc[4][4]) {
  const int t = threadIdx.x;
  const int w = t >> 6;
  const int lane = t & 63;
  const int wm = w >> 1, wn = w & 1;
  const int lm = lane & 15, quad = lane >> 4;

  for (int k0 = 0; k0 < K; k0 += 32) {
#pragma unroll
    for (int q = 0; q < 2; ++q) {
      const int ci = w * 128 + q * 64 + lane;   // 16B chunk index in tile
      const int row = ci >> 2;                  // tile row (0..127)
      const int cr = ci & 3;                    // 16B chunk within 64B row
      const bf16* ga = A + (size_t)(m0 + row) * K + (k0 + cr * 8);
      const bf16* gb = Bm + (size_t)(n0 + row) * K + (k0 + cr * 8);
      bf16* la = As + (w * 128 + q * 64) * 8;   // wave-uniform LDS base
      bf16* lb = Bs + (w * 128 + q * 64) * 8;
      stage16(ga, la);
      stage16(gb, lb);
    }
    __syncthreads();  // drains vmcnt(0) -> LDS tiles valid

    bf16x8 af[4], bfr[4];
#pragma unroll
    for (int i = 0; i < 4; ++i) {
      af[i]  = *(const bf16x8*)(As + ((wm * 64 + i * 16 + lm) * 32 + quad * 8));
      bfr[i] = *(const bf16x8*)(Bs + ((wn * 64 + i * 16 + lm) * 32 + quad * 8));
    }
#pragma unroll
    for (int mi = 0; mi < 4; ++mi)
#pragma unroll
      for (int ni = 0; ni < 4; ++ni)
        acc[mi][ni] = __builtin_amdgcn_mfma_f32_16x16x32_bf16(
            af[mi], bfr[ni], acc[mi][ni], 0, 0, 0);
    __syncthreads();  // protect LDS before next stage
  }
}

// ---------------------------------------------------------------- kernels ---

// LayerNorm: x(fp32) -> x_norm(bf16, scaled by 1/sqrt(D)); also init l=0,
// contrib=c[y[row]], maskcol=fs_classes[y[row]].
__global__ __launch_bounds__(256) void ln_kernel(
    const float* __restrict__ x, const int* __restrict__ y,
    const float* __restrict__ c, const int* __restrict__ fs,
    bf16* __restrict__ XN, float* __restrict__ lrow,
    float* __restrict__ contrib, int* __restrict__ maskcol) {
  const int row = blockIdx.x, t = threadIdx.x;
  const float4* xr = (const float4*)(x + (size_t)row * ND);
  float4 v0 = xr[t], v1 = xr[t + 256];
  float s = v0.x + v0.y + v0.z + v0.w + v1.x + v1.y + v1.z + v1.w;
  float q = v0.x * v0.x + v0.y * v0.y + v0.z * v0.z + v0.w * v0.w +
            v1.x * v1.x + v1.y * v1.y + v1.z * v1.z + v1.w * v1.w;
#pragma unroll
  for (int o = 32; o > 0; o >>= 1) {
    s += __shfl_down(s, o);
    q += __shfl_down(q, o);
  }
  __shared__ float ss[4], qq[4];
  const int w = t >> 6;
  if ((t & 63) == 0) { ss[w] = s; qq[w] = q; }
  __syncthreads();
  s = ss[0] + ss[1] + ss[2] + ss[3];
  q = qq[0] + qq[1] + qq[2] + qq[3];
  const float mu = s * (1.0f / ND);
  const float var = q * (1.0f / ND) - mu * mu;
  const float sc = rsqrtf(var + 1e-5f) * 0.02209708691207961f;  // 1/sqrt(2048)

  bf16x4 p0, p1;
  p0[0] = (bf16)((v0.x - mu) * sc); p0[1] = (bf16)((v0.y - mu) * sc);
  p0[2] = (bf16)((v0.z - mu) * sc); p0[3] = (bf16)((v0.w - mu) * sc);
  p1[0] = (bf16)((v1.x - mu) * sc); p1[1] = (bf16)((v1.y - mu) * sc);
  p1[2] = (bf16)((v1.z - mu) * sc); p1[3] = (bf16)((v1.w - mu) * sc);
  *(bf16x4*)(XN + (size_t)row * ND + t * 4) = p0;
  *(bf16x4*)(XN + (size_t)row * ND + 1024 + t * 4) = p1;

  if (t == 0) {
    lrow[row] = 0.0f;
    const int yi = y[row];
    contrib[row] = c[yi];
    maskcol[row] = fs[yi];
  }
}

// Transpose x (NB x ND fp32) -> XBT (ND x NB bf16)
__global__ __launch_bounds__(256) void transpose_kernel(
    const float* __restrict__ x, bf16* __restrict__ XBT) {
  __shared__ float tile[64][65];
  const int rb = blockIdx.x;  // batch tile (0..63)
  const int cb = blockIdx.y;  // feature tile (0..31)
  const int t = threadIdx.x;
  const int tx = t & 63, ty = t >> 6;
#pragma unroll
  for (int rr = ty; rr < 64; rr += 4)
    tile[rr][tx] = x[(size_t)(rb * 64 + rr) * ND + cb * 64 + tx];
  __syncthreads();
#pragma unroll
  for (int rr = ty; rr < 64; rr += 4)
    XBT[(size_t)(cb * 64 + rr) * NB + rb * 64 + tx] = (bf16)tile[tx][rr];
}

// GEMM1: P = exp(XN @ XN^T - mask) unnormalized (bf16), row sums -> lrow.
__global__ __launch_bounds__(256) void gemm_sim_kernel(
    const bf16* __restrict__ XN, bf16* __restrict__ P,
    float* __restrict__ lrow, const int* __restrict__ maskcol) {
  __shared__ bf16 As[128 * 32];
  __shared__ bf16 Bs[128 * 32];
  const int m0 = blockIdx.y * 128, n0 = blockIdx.x * 128;
  floatx4 acc[4][4];
#pragma unroll
  for (int i = 0; i < 4; ++i)
#pragma unroll
    for (int j = 0; j < 4; ++j) acc[i][j] = 0.0f;

  gemm_core(XN, XN, ND, m0, n0, As, Bs, acc);

  const int t = threadIdx.x, w = t >> 6, lane = t & 63;
  const int wm = w >> 1, wn = w & 1, lm = lane & 15, quad = lane >> 4;
  float rs[4][4];
#pragma unroll
  for (int i = 0; i < 4; ++i)
#pragma unroll
    for (int r = 0; r < 4; ++r) rs[i][r] = 0.0f;

#pragma unroll
  for (int ni = 0; ni < 4; ++ni) {
    const int gcol = n0 + wn * 64 + ni * 16 + lm;
    const int cm = maskcol[gcol];
#pragma unroll
    for (int mi = 0; mi < 4; ++mi) {
      floatx4 v = acc[mi][ni];
#pragma unroll
      for (int r = 0; r < 4; ++r) {
        const int grow = m0 + wm * 64 + mi * 16 + quad * 4 + r;
        const float p = ((grow == gcol) || cm) ? 0.0f : __expf(v[r]);
        const bf16 pb = (bf16)p;
        P[(size_t)grow * NB + gcol] = pb;
        rs[mi][r] += (float)pb;  // sum the quantized value -> exact normalize
      }
    }
  }
#pragma unroll
  for (int mi = 0; mi < 4; ++mi)
#pragma unroll
    for (int r = 0; r < 4; ++r) {
      float vsum = rs[mi][r];
      vsum += __shfl_xor(vsum, 1);
      vsum += __shfl_xor(vsum, 2);
      vsum += __shfl_xor(vsum, 4);
      vsum += __shfl_xor(vsum, 8);
      if (lm == 0)
        atomicAdd(&lrow[m0 + wm * 64 + mi * 16 + quad * 4 + r], vsum);
    }
}

// GEMM2: R = (P @ XBT^T)/l * contrib + x * (1-contrib)
__global__ __launch_bounds__(256) void gemm_recon_kernel(
    const bf16* __restrict__ P, const bf16* __restrict__ XBT,
    const float* __restrict__ x, const float* __restrict__ lrow,
    const float* __restrict__ contrib, float* __restrict__ R) {
  __shared__ bf16 As[128 * 32];
  __shared__ bf16 Bs[128 * 32];
  const int m0 = blockIdx.y * 128, n0 = blockIdx.x * 128;
  floatx4 acc[4][4];
#pragma unroll
  for (int i = 0; i < 4; ++i)
#pragma unroll
    for (int j = 0; j < 4; ++j) acc[i][j] = 0.0f;

  gemm_core(P, XBT, NB, m0, n0, As, Bs, acc);

  const int t = threadIdx.x, w = t >> 6, lane = t & 63;
  const int wm = w >> 1, wn = w & 1, lm = lane & 15, quad = lane >> 4;
#pragma unroll
  for (int mi = 0; mi < 4; ++mi) {
#pragma unroll
    for (int r = 0; r < 4; ++r) {
      const int grow = m0 + wm * 64 + mi * 16 + quad * 4 + r;
      const float inv = 1.0f / lrow[grow];
      const float ci = contrib[grow];
#pragma unroll
      for (int ni = 0; ni < 4; ++ni) {
        const int gcol = n0 + wn * 64 + ni * 16 + lm;
        const float rec = acc[mi][ni][r] * inv;
        const float xv = x[(size_t)grow * ND + gcol];
        R[(size_t)grow * ND + gcol] = rec * ci + xv * (1.0f - ci);
      }
    }
  }
}

// Mix: x_mix = a*R[i] + (1-a)*R[beta[i]]; y_mix from one-hots.
__global__ __launch_bounds__(256) void mix_kernel(
    const float* __restrict__ R, const float* __restrict__ alpha,
    const int* __restrict__ beta_idx, const int* __restrict__ y,
    float* __restrict__ out) {
  const int i = blockIdx.x, t = threadIdx.x;
  const float a = alpha[i];
  const int bi = beta_idx[i];
  const float4* Ri = (const float4*)(R + (size_t)i * ND);
  const float4* Rb = (const float4*)(R + (size_t)bi * ND);
  float4* o = (float4*)(out + (size_t)i * ND);
  const float b = 1.0f - a;
#pragma unroll
  for (int j = 0; j < 2; ++j) {
    const int idx = t + j * 256;
    float4 r = Ri[idx], g = Rb[idx], ov;
    ov.x = a * r.x + b * g.x;
    ov.y = a * r.y + b * g.y;
    ov.z = a * r.z + b * g.z;
    ov.w = a * r.w + b * g.w;
    o[idx] = ov;
  }
  if (t < NCLS) {
    const int yi = y[i], yb = y[bi];
    const float v = a * (t == yi ? 1.0f : 0.0f) + b * (t == yb ? 1.0f : 0.0f);
    out[(size_t)NB * ND + (size_t)i * NCLS + t] = v;
  }
}

// ------------------------------------------------------------------ launch --
extern "C" void kernel_launch(void* const* d_in, const int* in_sizes, int n_in,
                              void* d_out, int out_size, void* d_ws,
                              size_t ws_size, hipStream_t stream) {
  const float* x = (const float*)d_in[0];
  const int* y = (const int*)d_in[1];
  const float* alpha = (const float*)d_in[2];
  const int* beta = (const int*)d_in[3];
  const float* c = (const float*)d_in[4];
  const int* fs = (const int*)d_in[5];
  float* out = (float*)d_out;
  char* ws = (char*)d_ws;

  // workspace layout (bytes)
  bf16* XN  = (bf16*)(ws + 0);                       // 4096*2048*2 = 16 MiB
  bf16* XBT = (bf16*)(ws + 16777216);                // 2048*4096*2 = 16 MiB
  bf16* P   = (bf16*)(ws + 33554432);                // 4096*4096*2 = 32 MiB
  float* R  = (float*)(ws + 67108864);               // 4096*2048*4 = 32 MiB
  float* LR = (float*)(ws + 100663296);              // 4096*4
  float* CT = (float*)(ws + 100663296 + 16384);      // 4096*4
  int* MC   = (int*)(ws + 100663296 + 32768);        // 4096*4

  ln_kernel<<<NB, 256, 0, stream>>>(x, y, c, fs, XN, LR, CT, MC);
  transpose_kernel<<<dim3(64, 32), 256, 0, stream>>>(x, XBT);
  gemm_sim_kernel<<<dim3(32, 32), 256, 0, stream>>>(XN, P, LR, MC);
  gemm_recon_kernel<<<dim3(16, 32), 256, 0, stream>>>(P, XBT, x, LR, CT, R);
  mix_kernel<<<NB, 256, 0, stream>>>(R, alpha, beta, y, out);
}

// Round 2
// 293.585 us; speedup vs baseline: 1.0392x; 1.0392x over previous
//
#include <hip/hip_runtime.h>
#include <cstdint>
#include <cstddef>

typedef __bf16 bf16;
typedef __bf16 bf16x4 __attribute__((ext_vector_type(4)));
typedef __bf16 bf16x8 __attribute__((ext_vector_type(8)));
typedef float floatx4 __attribute__((ext_vector_type(4)));

#define NB 4096   // batch
#define ND 2048   // feature dim
#define NCLS 64   // classes

// ---------------------------------------------------------------- staging ---
__device__ __forceinline__ void stage16(const void* g, void* l) {
  // async global -> LDS, 16B per lane, LDS dest = wave-uniform base + lane*16
  __builtin_amdgcn_global_load_lds(
      (__attribute__((address_space(1))) unsigned int*)g,
      (__attribute__((address_space(3))) unsigned int*)l, 16, 0, 0);
}

// ------------------------------------------------------------- GEMM core ----
// C[M][N] = A[M][K] * B[N][K]^T, bf16 inputs, fp32 accum.
// Block: 256 thr = 4 waves (2x2), tile 128x128, BK=32.
// XOR chunk swizzle: LDS slot r*4+c' holds global 16B chunk c = c'^(r&3);
// fragment reads use chunk quad^(lm&3) -> halves ds_read_b128 bank conflicts.
__device__ __forceinline__ void gemm_core(const bf16* __restrict__ A,
                                          const bf16* __restrict__ Bm, int K,
                                          int m0, int n0, bf16* As, bf16* Bs,
                                          floatx4 acc[4][4]) {
  const int t = threadIdx.x;
  const int w = t >> 6;
  const int lane = t & 63;
  const int wm = w >> 1, wn = w & 1;
  const int lm = lane & 15, quad = lane >> 4;

  for (int k0 = 0; k0 < K; k0 += 32) {
#pragma unroll
    for (int q = 0; q < 2; ++q) {
      const int ci = w * 128 + q * 64 + lane;     // LDS 16B-slot index in tile
      const int row = ci >> 2;                    // tile row (0..127)
      const int cr = (ci & 3) ^ (row & 3);        // swizzled global chunk
      const bf16* ga = A + (size_t)(m0 + row) * K + (k0 + cr * 8);
      const bf16* gb = Bm + (size_t)(n0 + row) * K + (k0 + cr * 8);
      bf16* la = As + (w * 128 + q * 64) * 8;     // wave-uniform LDS base
      bf16* lb = Bs + (w * 128 + q * 64) * 8;
      stage16(ga, la);
      stage16(gb, lb);
    }
    __syncthreads();  // drains vmcnt(0) -> LDS tiles valid

    bf16x8 af[4], bfr[4];
#pragma unroll
    for (int i = 0; i < 4; ++i) {
      const int qa = (quad ^ (lm & 3)) * 8;
      af[i]  = *(const bf16x8*)(As + (wm * 64 + i * 16 + lm) * 32 + qa);
      bfr[i] = *(const bf16x8*)(Bs + (wn * 64 + i * 16 + lm) * 32 + qa);
    }
#pragma unroll
    for (int mi = 0; mi < 4; ++mi)
#pragma unroll
      for (int ni = 0; ni < 4; ++ni)
        acc[mi][ni] = __builtin_amdgcn_mfma_f32_16x16x32_bf16(
            af[mi], bfr[ni], acc[mi][ni], 0, 0, 0);
    __syncthreads();  // protect LDS before next stage
  }
}

// ---------------------------------------------------------------- kernels ---

// LayerNorm: x(fp32) -> x_norm(bf16, scaled by 1/sqrt(D)); also init l=0,
// contrib=c[y[row]], maskcol=fs_classes[y[row]].
__global__ __launch_bounds__(256) void ln_kernel(
    const float* __restrict__ x, const int* __restrict__ y,
    const float* __restrict__ c, const int* __restrict__ fs,
    bf16* __restrict__ XN, float* __restrict__ lrow,
    float* __restrict__ contrib, int* __restrict__ maskcol) {
  const int row = blockIdx.x, t = threadIdx.x;
  const float4* xr = (const float4*)(x + (size_t)row * ND);
  float4 v0 = xr[t], v1 = xr[t + 256];
  float s = v0.x + v0.y + v0.z + v0.w + v1.x + v1.y + v1.z + v1.w;
  float q = v0.x * v0.x + v0.y * v0.y + v0.z * v0.z + v0.w * v0.w +
            v1.x * v1.x + v1.y * v1.y + v1.z * v1.z + v1.w * v1.w;
#pragma unroll
  for (int o = 32; o > 0; o >>= 1) {
    s += __shfl_down(s, o);
    q += __shfl_down(q, o);
  }
  __shared__ float ss[4], qq[4];
  const int w = t >> 6;
  if ((t & 63) == 0) { ss[w] = s; qq[w] = q; }
  __syncthreads();
  s = ss[0] + ss[1] + ss[2] + ss[3];
  q = qq[0] + qq[1] + qq[2] + qq[3];
  const float mu = s * (1.0f / ND);
  const float var = q * (1.0f / ND) - mu * mu;
  const float sc = rsqrtf(var + 1e-5f) * 0.02209708691207961f;  // 1/sqrt(2048)

  bf16x4 p0, p1;
  p0[0] = (bf16)((v0.x - mu) * sc); p0[1] = (bf16)((v0.y - mu) * sc);
  p0[2] = (bf16)((v0.z - mu) * sc); p0[3] = (bf16)((v0.w - mu) * sc);
  p1[0] = (bf16)((v1.x - mu) * sc); p1[1] = (bf16)((v1.y - mu) * sc);
  p1[2] = (bf16)((v1.z - mu) * sc); p1[3] = (bf16)((v1.w - mu) * sc);
  *(bf16x4*)(XN + (size_t)row * ND + t * 4) = p0;
  *(bf16x4*)(XN + (size_t)row * ND + 1024 + t * 4) = p1;

  if (t == 0) {
    lrow[row] = 0.0f;
    const int yi = y[row];
    contrib[row] = c[yi];
    maskcol[row] = fs[yi];
  }
}

// Transpose x (NB x ND fp32) -> XBT (ND x NB bf16)
__global__ __launch_bounds__(256) void transpose_kernel(
    const float* __restrict__ x, bf16* __restrict__ XBT) {
  __shared__ float tile[64][65];
  const int rb = blockIdx.x;  // batch tile (0..63)
  const int cb = blockIdx.y;  // feature tile (0..31)
  const int t = threadIdx.x;
  const int tx = t & 63, ty = t >> 6;
#pragma unroll
  for (int rr = ty; rr < 64; rr += 4)
    tile[rr][tx] = x[(size_t)(rb * 64 + rr) * ND + cb * 64 + tx];
  __syncthreads();
#pragma unroll
  for (int rr = ty; rr < 64; rr += 4)
    XBT[(size_t)(cb * 64 + rr) * NB + rb * 64 + tx] = (bf16)tile[tx][rr];
}

// GEMM1 (triangular): for block (bi<=bj), S = XN_i @ XN_j^T; exp(S) is
// symmetric (mask is column-only + diag). Write P tile (bi,bj) with col mask
// of Bj and P^T tile (bj,bi) with col mask of Bi; accumulate both row sums.
// Output tiles go through LDS for coalesced bf16x8 stores.
#define EPS_STRIDE 136  // 128 + 8 pad, bf16 elements
__global__ __launch_bounds__(256) void gemm_sim_kernel(
    const bf16* __restrict__ XN, bf16* __restrict__ P,
    float* __restrict__ lrow, const int* __restrict__ maskcol) {
  __shared__ bf16 smem[128 * EPS_STRIDE];  // 34816 B; K-loop uses first 16 KB
  bf16* As = smem;
  bf16* Bs = smem + 4096;

  // triangular decode: b = bj*(bj+1)/2 + bi, bi <= bj
  const int b = blockIdx.x;
  int bj = (int)((sqrtf(8.0f * (float)b + 1.0f) - 1.0f) * 0.5f);
  while ((bj + 1) * (bj + 2) / 2 <= b) ++bj;
  while (bj * (bj + 1) / 2 > b) --bj;
  const int bi = b - bj * (bj + 1) / 2;
  const int m0 = bi * 128, n0 = bj * 128;

  floatx4 acc[4][4];
#pragma unroll
  for (int i = 0; i < 4; ++i)
#pragma unroll
    for (int j = 0; j < 4; ++j) acc[i][j] = 0.0f;

  gemm_core(XN, XN, ND, m0, n0, As, Bs, acc);

  const int t = threadIdx.x, w = t >> 6, lane = t & 63;
  const int wm = w >> 1, wn = w & 1, lm = lane & 15, quad = lane >> 4;

  // column masks for Pn (cols in Bj), row masks for Pt (rows of tile in Bi)
  int cmj[4];
#pragma unroll
  for (int ni = 0; ni < 4; ++ni) cmj[ni] = maskcol[n0 + wn * 64 + ni * 16 + lm];
  int rmk[4][4];
#pragma unroll
  for (int mi = 0; mi < 4; ++mi)
#pragma unroll
    for (int r = 0; r < 4; ++r)
      rmk[mi][r] = maskcol[m0 + wm * 64 + mi * 16 + quad * 4 + r];

  // exp in place (diag -> 0), Pn row sums of quantized values
  float rs[4][4];
#pragma unroll
  for (int mi = 0; mi < 4; ++mi)
#pragma unroll
    for (int r = 0; r < 4; ++r) rs[mi][r] = 0.0f;

#pragma unroll
  for (int ni = 0; ni < 4; ++ni) {
    const int gcol = n0 + wn * 64 + ni * 16 + lm;
#pragma unroll
    for (int mi = 0; mi < 4; ++mi) {
#pragma unroll
      for (int r = 0; r < 4; ++r) {
        const int grow = m0 + wm * 64 + mi * 16 + quad * 4 + r;
        float e = (grow == gcol) ? 0.0f : __expf(acc[mi][ni][r]);
        acc[mi][ni][r] = e;
        const bf16 pnb = (bf16)(cmj[ni] ? 0.0f : e);
        rs[mi][r] += (float)pnb;
      }
    }
  }
#pragma unroll
  for (int mi = 0; mi < 4; ++mi)
#pragma unroll
    for (int r = 0; r < 4; ++r) {
      float vsum = rs[mi][r];
      vsum += __shfl_xor(vsum, 1);
      vsum += __shfl_xor(vsum, 2);
      vsum += __shfl_xor(vsum, 4);
      vsum += __shfl_xor(vsum, 8);
      if (lm == 0)
        atomicAdd(&lrow[m0 + wm * 64 + mi * 16 + quad * 4 + r], vsum);
    }

  // ---- Pn tile -> LDS -> coalesced store at (bi,bj)
  // (gemm_core ended with __syncthreads; smem free to reuse)
#pragma unroll
  for (int ni = 0; ni < 4; ++ni) {
    const int col = wn * 64 + ni * 16 + lm;
#pragma unroll
    for (int mi = 0; mi < 4; ++mi)
#pragma unroll
      for (int r = 0; r < 4; ++r) {
        const int row = wm * 64 + mi * 16 + quad * 4 + r;
        smem[row * EPS_STRIDE + col] = (bf16)(cmj[ni] ? 0.0f : acc[mi][ni][r]);
      }
  }
  __syncthreads();
#pragma unroll
  for (int it = 0; it < 8; ++it) {
    const int row = it * 16 + (t >> 4), ch = t & 15;
    bf16x8 v = *(const bf16x8*)(smem + row * EPS_STRIDE + ch * 8);
    *(bf16x8*)(P + (size_t)(m0 + row) * NB + n0 + ch * 8) = v;
  }

  if (bi != bj) {
    __syncthreads();
    // ---- Pt tile: value = rowmask ? 0 : e; col sums -> lrow[Bj rows]
#pragma unroll
    for (int ni = 0; ni < 4; ++ni) {
      const int tc = wn * 64 + ni * 16 + lm;  // Pt row = original col
      float cs = 0.0f;
#pragma unroll
      for (int mi = 0; mi < 4; ++mi) {
        bf16x4 pk;
#pragma unroll
        for (int r = 0; r < 4; ++r) {
          const bf16 ptb = (bf16)(rmk[mi][r] ? 0.0f : acc[mi][ni][r]);
          pk[r] = ptb;
          cs += (float)ptb;
        }
        // Pt col block = original rows; 4 contiguous cols -> 8B write
        *(bf16x4*)(smem + tc * EPS_STRIDE + wm * 64 + mi * 16 + quad * 4) = pk;
      }
      cs += __shfl_xor(cs, 16);
      cs += __shfl_xor(cs, 32);
      if (quad == 0) atomicAdd(&lrow[n0 + tc], cs);
    }
    __syncthreads();
#pragma unroll
    for (int it = 0; it < 8; ++it) {
      const int row = it * 16 + (t >> 4), ch = t & 15;
      bf16x8 v = *(const bf16x8*)(smem + row * EPS_STRIDE + ch * 8);
      *(bf16x8*)(P + (size_t)(n0 + row) * NB + m0 + ch * 8) = v;
    }
  }
}

// GEMM2: R = (P @ XBT^T)/l * contrib + x * (1-contrib)
__global__ __launch_bounds__(256) void gemm_recon_kernel(
    const bf16* __restrict__ P, const bf16* __restrict__ XBT,
    const float* __restrict__ x, const float* __restrict__ lrow,
    const float* __restrict__ contrib, float* __restrict__ R) {
  __shared__ bf16 As[128 * 32];
  __shared__ bf16 Bs[128 * 32];
  const int m0 = blockIdx.y * 128, n0 = blockIdx.x * 128;
  floatx4 acc[4][4];
#pragma unroll
  for (int i = 0; i < 4; ++i)
#pragma unroll
    for (int j = 0; j < 4; ++j) acc[i][j] = 0.0f;

  gemm_core(P, XBT, NB, m0, n0, As, Bs, acc);

  const int t = threadIdx.x, w = t >> 6, lane = t & 63;
  const int wm = w >> 1, wn = w & 1, lm = lane & 15, quad = lane >> 4;
#pragma unroll
  for (int mi = 0; mi < 4; ++mi) {
#pragma unroll
    for (int r = 0; r < 4; ++r) {
      const int grow = m0 + wm * 64 + mi * 16 + quad * 4 + r;
      const float inv = 1.0f / lrow[grow];
      const float ci = contrib[grow];
#pragma unroll
      for (int ni = 0; ni < 4; ++ni) {
        const int gcol = n0 + wn * 64 + ni * 16 + lm;
        const float rec = acc[mi][ni][r] * inv;
        const float xv = x[(size_t)grow * ND + gcol];
        R[(size_t)grow * ND + gcol] = rec * ci + xv * (1.0f - ci);
      }
    }
  }
}

// Mix: x_mix = a*R[i] + (1-a)*R[beta[i]]; y_mix from one-hots.
__global__ __launch_bounds__(256) void mix_kernel(
    const float* __restrict__ R, const float* __restrict__ alpha,
    const int* __restrict__ beta_idx, const int* __restrict__ y,
    float* __restrict__ out) {
  const int i = blockIdx.x, t = threadIdx.x;
  const float a = alpha[i];
  const int bi = beta_idx[i];
  const float4* Ri = (const float4*)(R + (size_t)i * ND);
  const float4* Rb = (const float4*)(R + (size_t)bi * ND);
  float4* o = (float4*)(out + (size_t)i * ND);
  const float b = 1.0f - a;
#pragma unroll
  for (int j = 0; j < 2; ++j) {
    const int idx = t + j * 256;
    float4 r = Ri[idx], g = Rb[idx], ov;
    ov.x = a * r.x + b * g.x;
    ov.y = a * r.y + b * g.y;
    ov.z = a * r.z + b * g.z;
    ov.w = a * r.w + b * g.w;
    o[idx] = ov;
  }
  if (t < NCLS) {
    const int yi = y[i], yb = y[bi];
    const float v = a * (t == yi ? 1.0f : 0.0f) + b * (t == yb ? 1.0f : 0.0f);
    out[(size_t)NB * ND + (size_t)i * NCLS + t] = v;
  }
}

// ------------------------------------------------------------------ launch --
extern "C" void kernel_launch(void* const* d_in, const int* in_sizes, int n_in,
                              void* d_out, int out_size, void* d_ws,
                              size_t ws_size, hipStream_t stream) {
  const float* x = (const float*)d_in[0];
  const int* y = (const int*)d_in[1];
  const float* alpha = (const float*)d_in[2];
  const int* beta = (const int*)d_in[3];
  const float* c = (const float*)d_in[4];
  const int* fs = (const int*)d_in[5];
  float* out = (float*)d_out;
  char* ws = (char*)d_ws;

  // workspace layout (bytes)
  bf16* XN  = (bf16*)(ws + 0);                       // 4096*2048*2 = 16 MiB
  bf16* XBT = (bf16*)(ws + 16777216);                // 2048*4096*2 = 16 MiB
  bf16* P   = (bf16*)(ws + 33554432);                // 4096*4096*2 = 32 MiB
  float* R  = (float*)(ws + 67108864);               // 4096*2048*4 = 32 MiB
  float* LR = (float*)(ws + 100663296);              // 4096*4
  float* CT = (float*)(ws + 100663296 + 16384);      // 4096*4
  int* MC   = (int*)(ws + 100663296 + 32768);        // 4096*4

  ln_kernel<<<NB, 256, 0, stream>>>(x, y, c, fs, XN, LR, CT, MC);
  transpose_kernel<<<dim3(64, 32), 256, 0, stream>>>(x, XBT);
  gemm_sim_kernel<<<528, 256, 0, stream>>>(XN, P, LR, MC);
  gemm_recon_kernel<<<dim3(16, 32), 256, 0, stream>>>(P, XBT, x, LR, CT, R);
  mix_kernel<<<NB, 256, 0, stream>>>(R, alpha, beta, y, out);
}

// Round 3
// 215.763 us; speedup vs baseline: 1.4141x; 1.3607x over previous
//
#include <hip/hip_runtime.h>
#include <cstdint>
#include <cstddef>

typedef float floatx4 __attribute__((ext_vector_type(4)));
typedef int intx8 __attribute__((ext_vector_type(8)));

#define NB 4096   // batch
#define ND 2048   // feature dim
#define NCLS 64   // classes
#define TSTRIDE 144  // epilogue LDS row stride (bytes), 16B-aligned

// ---------------------------------------------------------------- staging ---
__device__ __forceinline__ void stage16(const void* g, void* l) {
  // async global -> LDS, 16B per lane, LDS dest = wave-uniform base + lane*16
  __builtin_amdgcn_global_load_lds(
      (__attribute__((address_space(1))) unsigned int*)g,
      (__attribute__((address_space(3))) unsigned int*)l, 16, 0, 0);
}

// fp8 e4m3 (OCP) converts, RNE via V_CVT_PK_FP8_F32
__device__ __forceinline__ unsigned char fp8x1(float f) {
  return (unsigned char)(__builtin_amdgcn_cvt_pk_fp8_f32(f, f, 0, false) & 0xFF);
}
__device__ __forceinline__ int fp8x4(float f0, float f1, float f2, float f3) {
  int d = __builtin_amdgcn_cvt_pk_fp8_f32(f0, f1, 0, false);
  return __builtin_amdgcn_cvt_pk_fp8_f32(f2, f3, d, true);
}

// ------------------------------------------------------------- GEMM core ----
// C[128][BROWS... wait N-tile = NI*32] = A[128][K] * B[N][K]^T, fp8 inputs,
// fp32 accum via mfma_scale 16x16x128 (scales = 1.0 -> byte 127).
// Block: 256 thr = 4 waves (2x2); wave quadrant 64 x (NI*16).
// LDS: rows of 128 B (8 x 16B chunks), chunk XOR-swizzled by (row&7).
template <int BROWS, int NI>
__device__ __forceinline__ void gemm_core8(const unsigned char* __restrict__ A,
                                           const unsigned char* __restrict__ B,
                                           int K, int m0, int n0,
                                           unsigned char* As, unsigned char* Bs,
                                           floatx4 acc[4][NI]) {
  const int t = threadIdx.x;
  const int w = t >> 6;
  const int lane = t & 63;
  const int wm = w >> 1, wn = w & 1;
  const int lm = lane & 15, quad = lane >> 4;

  for (int k0 = 0; k0 < K; k0 += 128) {
    // stage A tile: 128 rows x 128 B = 1024 16B slots
#pragma unroll
    for (int q = 0; q < 4; ++q) {
      const int slot = w * 256 + q * 64 + lane;
      const int row = slot >> 3;
      const int cc = (slot & 7) ^ (row & 7);  // swizzled global chunk
      stage16(A + (size_t)(m0 + row) * K + (k0 + cc * 16),
              As + (w * 256 + q * 64) * 16);
    }
    // stage B tile: BROWS rows
#pragma unroll
    for (int q = 0; q < BROWS / 32; ++q) {
      const int slot = w * (BROWS * 2) + q * 64 + lane;
      const int row = slot >> 3;
      const int cc = (slot & 7) ^ (row & 7);
      stage16(B + (size_t)(n0 + row) * K + (k0 + cc * 16),
              Bs + (w * (BROWS * 2) + q * 64) * 16);
    }
    __syncthreads();  // drains vmcnt(0) -> LDS tiles valid

    intx8 af[4], bfr[NI];
#pragma unroll
    for (int i = 0; i < 4; ++i) {
      const int row = wm * 64 + i * 16 + lm;
      const int c0 = (quad * 2) ^ (row & 7);
      const int4 lo = *(const int4*)(As + row * 128 + c0 * 16);
      const int4 hi = *(const int4*)(As + row * 128 + (c0 ^ 1) * 16);
      af[i][0] = lo.x; af[i][1] = lo.y; af[i][2] = lo.z; af[i][3] = lo.w;
      af[i][4] = hi.x; af[i][5] = hi.y; af[i][6] = hi.z; af[i][7] = hi.w;
    }
#pragma unroll
    for (int i = 0; i < NI; ++i) {
      const int row = wn * (NI * 16) + i * 16 + lm;
      const int c0 = (quad * 2) ^ (row & 7);
      const int4 lo = *(const int4*)(Bs + row * 128 + c0 * 16);
      const int4 hi = *(const int4*)(Bs + row * 128 + (c0 ^ 1) * 16);
      bfr[i][0] = lo.x; bfr[i][1] = lo.y; bfr[i][2] = lo.z; bfr[i][3] = lo.w;
      bfr[i][4] = hi.x; bfr[i][5] = hi.y; bfr[i][6] = hi.z; bfr[i][7] = hi.w;
    }
#pragma unroll
    for (int mi = 0; mi < 4; ++mi)
#pragma unroll
      for (int ni = 0; ni < NI; ++ni)
        acc[mi][ni] = __builtin_amdgcn_mfma_scale_f32_16x16x128_f8f6f4(
            af[mi], bfr[ni], acc[mi][ni], 0, 0, 0, 127, 0, 127);
    __syncthreads();  // protect LDS before next stage
  }
}

// ---------------------------------------------------------------- kernels ---

// LayerNorm: x(fp32) -> XN8 = fp8(x_norm * 32)  (x_norm scaled by 1/sqrt(D));
// the *32 avoids e4m3 subnormal squash; GEMM1 divides acc by 1024.
__global__ __launch_bounds__(256) void ln_kernel(
    const float* __restrict__ x, const int* __restrict__ y,
    const float* __restrict__ c, const int* __restrict__ fs,
    unsigned char* __restrict__ XN8, float* __restrict__ lrow,
    float* __restrict__ contrib, int* __restrict__ maskcol) {
  const int row = blockIdx.x, t = threadIdx.x;
  const float4* xr = (const float4*)(x + (size_t)row * ND);
  float4 v0 = xr[t], v1 = xr[t + 256];
  float s = v0.x + v0.y + v0.z + v0.w + v1.x + v1.y + v1.z + v1.w;
  float q = v0.x * v0.x + v0.y * v0.y + v0.z * v0.z + v0.w * v0.w +
            v1.x * v1.x + v1.y * v1.y + v1.z * v1.z + v1.w * v1.w;
#pragma unroll
  for (int o = 32; o > 0; o >>= 1) {
    s += __shfl_down(s, o);
    q += __shfl_down(q, o);
  }
  __shared__ float ss[4], qq[4];
  const int w = t >> 6;
  if ((t & 63) == 0) { ss[w] = s; qq[w] = q; }
  __syncthreads();
  s = ss[0] + ss[1] + ss[2] + ss[3];
  q = qq[0] + qq[1] + qq[2] + qq[3];
  const float mu = s * (1.0f / ND);
  const float var = q * (1.0f / ND) - mu * mu;
  const float sc =
      rsqrtf(var + 1e-5f) * 0.02209708691207961f * 32.0f;  // /sqrt(2048)*32

  int* orow = (int*)(XN8 + (size_t)row * ND);
  orow[t] = fp8x4((v0.x - mu) * sc, (v0.y - mu) * sc, (v0.z - mu) * sc,
                  (v0.w - mu) * sc);
  orow[256 + t] = fp8x4((v1.x - mu) * sc, (v1.y - mu) * sc, (v1.z - mu) * sc,
                        (v1.w - mu) * sc);

  if (t == 0) {
    lrow[row] = 0.0f;
    const int yi = y[row];
    contrib[row] = c[yi];
    maskcol[row] = fs[yi];
  }
}

// Transpose x (NB x ND fp32) -> XBT8 (ND x NB fp8)
__global__ __launch_bounds__(256) void transpose_kernel(
    const float* __restrict__ x, unsigned char* __restrict__ XBT8) {
  __shared__ float tile[64][65];
  const int rb = blockIdx.x;  // batch tile (0..63)
  const int cb = blockIdx.y;  // feature tile (0..31)
  const int t = threadIdx.x;
  const int tx = t & 63, ty = t >> 6;
#pragma unroll
  for (int rr = ty; rr < 64; rr += 4)
    tile[rr][tx] = x[(size_t)(rb * 64 + rr) * ND + cb * 64 + tx];
  __syncthreads();
  const int ro = t >> 2;  // out row within feature tile
  const int co = t & 3;   // 16-byte chunk within batch tile
  int4 v;
  {
    const int j = co * 16;
    v.x = fp8x4(tile[j + 0][ro], tile[j + 1][ro], tile[j + 2][ro], tile[j + 3][ro]);
    v.y = fp8x4(tile[j + 4][ro], tile[j + 5][ro], tile[j + 6][ro], tile[j + 7][ro]);
    v.z = fp8x4(tile[j + 8][ro], tile[j + 9][ro], tile[j + 10][ro], tile[j + 11][ro]);
    v.w = fp8x4(tile[j + 12][ro], tile[j + 13][ro], tile[j + 14][ro], tile[j + 15][ro]);
  }
  *(int4*)(XBT8 + (size_t)(cb * 64 + ro) * NB + rb * 64 + co * 16) = v;
}

// GEMM1 (triangular): for block (bi<=bj), acc = 1024*sim; e = exp(acc/1024);
// write Pn tile (bi,bj) fp8 w/ col mask of Bj and Pt tile (bj,bi) w/ col mask
// of Bi; accumulate row sums of unquantized e (l rel-err ~3e-4, negligible).
__global__ __launch_bounds__(256) void gemm_sim_kernel(
    const unsigned char* __restrict__ XN8, unsigned char* __restrict__ P8,
    float* __restrict__ lrow, const int* __restrict__ maskcol) {
  __shared__ unsigned char smem[32768];
  unsigned char* As = smem;
  unsigned char* Bs = smem + 16384;

  // triangular decode: b = bj*(bj+1)/2 + bi, bi <= bj
  const int b = blockIdx.x;
  int bj = (int)((sqrtf(8.0f * (float)b + 1.0f) - 1.0f) * 0.5f);
  while ((bj + 1) * (bj + 2) / 2 <= b) ++bj;
  while (bj * (bj + 1) / 2 > b) --bj;
  const int bi = b - bj * (bj + 1) / 2;
  const int m0 = bi * 128, n0 = bj * 128;

  floatx4 acc[4][4];
#pragma unroll
  for (int i = 0; i < 4; ++i)
#pragma unroll
    for (int j = 0; j < 4; ++j) acc[i][j] = 0.0f;

  gemm_core8<128, 4>(XN8, XN8, ND, m0, n0, As, Bs, acc);

  const int t = threadIdx.x, w = t >> 6, lane = t & 63;
  const int wm = w >> 1, wn = w & 1, lm = lane & 15, quad = lane >> 4;

  int cmj[4];
#pragma unroll
  for (int ni = 0; ni < 4; ++ni) cmj[ni] = maskcol[n0 + wn * 64 + ni * 16 + lm];
  int rmk[4][4];
#pragma unroll
  for (int mi = 0; mi < 4; ++mi)
#pragma unroll
    for (int r = 0; r < 4; ++r)
      rmk[mi][r] = maskcol[m0 + wm * 64 + mi * 16 + quad * 4 + r];

  // exp in place (diag -> 0), Pn row sums
  float rs[4][4];
#pragma unroll
  for (int mi = 0; mi < 4; ++mi)
#pragma unroll
    for (int r = 0; r < 4; ++r) rs[mi][r] = 0.0f;

#pragma unroll
  for (int ni = 0; ni < 4; ++ni) {
    const int gcol = n0 + wn * 64 + ni * 16 + lm;
#pragma unroll
    for (int mi = 0; mi < 4; ++mi) {
#pragma unroll
      for (int r = 0; r < 4; ++r) {
        const int grow = m0 + wm * 64 + mi * 16 + quad * 4 + r;
        float e = (grow == gcol) ? 0.0f
                                 : __expf(acc[mi][ni][r] * 0.0009765625f);
        acc[mi][ni][r] = e;
        rs[mi][r] += cmj[ni] ? 0.0f : e;
      }
    }
  }
#pragma unroll
  for (int mi = 0; mi < 4; ++mi)
#pragma unroll
    for (int r = 0; r < 4; ++r) {
      float vsum = rs[mi][r];
      vsum += __shfl_xor(vsum, 1);
      vsum += __shfl_xor(vsum, 2);
      vsum += __shfl_xor(vsum, 4);
      vsum += __shfl_xor(vsum, 8);
      if (lm == 0)
        atomicAdd(&lrow[m0 + wm * 64 + mi * 16 + quad * 4 + r], vsum);
    }

  // ---- Pn tile -> LDS (byte scatter) -> coalesced b128 store at (bi,bj)
#pragma unroll
  for (int ni = 0; ni < 4; ++ni) {
    const int col = wn * 64 + ni * 16 + lm;
#pragma unroll
    for (int mi = 0; mi < 4; ++mi)
#pragma unroll
      for (int r = 0; r < 4; ++r) {
        const int row = wm * 64 + mi * 16 + quad * 4 + r;
        smem[row * TSTRIDE + col] = fp8x1(cmj[ni] ? 0.0f : acc[mi][ni][r]);
      }
  }
  __syncthreads();
#pragma unroll
  for (int it = 0; it < 4; ++it) {
    const int row = it * 32 + (t >> 3), ch = t & 7;
    int4 v = *(const int4*)(smem + row * TSTRIDE + ch * 16);
    *(int4*)(P8 + (size_t)(m0 + row) * NB + n0 + ch * 16) = v;
  }

  if (bi != bj) {
    __syncthreads();
    // ---- Pt tile: in-lane dword pack (4 rows = 4 consecutive Pt cols)
#pragma unroll
    for (int ni = 0; ni < 4; ++ni) {
      const int tc = wn * 64 + ni * 16 + lm;  // Pt row = original col
      float cs = 0.0f;
#pragma unroll
      for (int mi = 0; mi < 4; ++mi) {
        float g0 = rmk[mi][0] ? 0.0f : acc[mi][ni][0];
        float g1 = rmk[mi][1] ? 0.0f : acc[mi][ni][1];
        float g2 = rmk[mi][2] ? 0.0f : acc[mi][ni][2];
        float g3 = rmk[mi][3] ? 0.0f : acc[mi][ni][3];
        cs += g0 + g1 + g2 + g3;
        *(int*)(smem + tc * TSTRIDE + wm * 64 + mi * 16 + quad * 4) =
            fp8x4(g0, g1, g2, g3);
      }
      cs += __shfl_xor(cs, 16);
      cs += __shfl_xor(cs, 32);
      if (quad == 0) atomicAdd(&lrow[n0 + tc], cs);
    }
    __syncthreads();
#pragma unroll
    for (int it = 0; it < 4; ++it) {
      const int row = it * 32 + (t >> 3), ch = t & 7;
      int4 v = *(const int4*)(smem + row * TSTRIDE + ch * 16);
      *(int4*)(P8 + (size_t)(n0 + row) * NB + m0 + ch * 16) = v;
    }
  }
}

// GEMM2: R = (P8 @ XBT8^T)/l * contrib + x*(1-contrib). 128x64 tiles ->
// grid 1024 blocks (4/CU) to fix R2's grid starvation; operands L2-resident.
__global__ __launch_bounds__(256) void gemm_recon_kernel(
    const unsigned char* __restrict__ P8, const unsigned char* __restrict__ XBT8,
    const float* __restrict__ x, const float* __restrict__ lrow,
    const float* __restrict__ contrib, float* __restrict__ R) {
  __shared__ unsigned char smem[24576];
  unsigned char* As = smem;           // 16 KB
  unsigned char* Bs = smem + 16384;   // 8 KB
  const int m0 = blockIdx.y * 128, n0 = blockIdx.x * 64;
  floatx4 acc[4][2];
#pragma unroll
  for (int i = 0; i < 4; ++i)
#pragma unroll
    for (int j = 0; j < 2; ++j) acc[i][j] = 0.0f;

  gemm_core8<64, 2>(P8, XBT8, NB, m0, n0, As, Bs, acc);

  const int t = threadIdx.x, w = t >> 6, lane = t & 63;
  const int wm = w >> 1, wn = w & 1, lm = lane & 15, quad = lane >> 4;
#pragma unroll
  for (int mi = 0; mi < 4; ++mi) {
#pragma unroll
    for (int r = 0; r < 4; ++r) {
      const int grow = m0 + wm * 64 + mi * 16 + quad * 4 + r;
      const float inv = 1.0f / lrow[grow];
      const float ci = contrib[grow];
#pragma unroll
      for (int ni = 0; ni < 2; ++ni) {
        const int gcol = n0 + wn * 32 + ni * 16 + lm;
        const float rec = acc[mi][ni][r] * inv;
        const float xv = x[(size_t)grow * ND + gcol];
        R[(size_t)grow * ND + gcol] = rec * ci + xv * (1.0f - ci);
      }
    }
  }
}

// Mix: x_mix = a*R[i] + (1-a)*R[beta[i]]; y_mix from one-hots.
__global__ __launch_bounds__(256) void mix_kernel(
    const float* __restrict__ R, const float* __restrict__ alpha,
    const int* __restrict__ beta_idx, const int* __restrict__ y,
    float* __restrict__ out) {
  const int i = blockIdx.x, t = threadIdx.x;
  const float a = alpha[i];
  const int bi = beta_idx[i];
  const float4* Ri = (const float4*)(R + (size_t)i * ND);
  const float4* Rb = (const float4*)(R + (size_t)bi * ND);
  float4* o = (float4*)(out + (size_t)i * ND);
  const float b = 1.0f - a;
#pragma unroll
  for (int j = 0; j < 2; ++j) {
    const int idx = t + j * 256;
    float4 r = Ri[idx], g = Rb[idx], ov;
    ov.x = a * r.x + b * g.x;
    ov.y = a * r.y + b * g.y;
    ov.z = a * r.z + b * g.z;
    ov.w = a * r.w + b * g.w;
    o[idx] = ov;
  }
  if (t < NCLS) {
    const int yi = y[i], yb = y[bi];
    const float v = a * (t == yi ? 1.0f : 0.0f) + b * (t == yb ? 1.0f : 0.0f);
    out[(size_t)NB * ND + (size_t)i * NCLS + t] = v;
  }
}

// ------------------------------------------------------------------ launch --
extern "C" void kernel_launch(void* const* d_in, const int* in_sizes, int n_in,
                              void* d_out, int out_size, void* d_ws,
                              size_t ws_size, hipStream_t stream) {
  const float* x = (const float*)d_in[0];
  const int* y = (const int*)d_in[1];
  const float* alpha = (const float*)d_in[2];
  const int* beta = (const int*)d_in[3];
  const float* c = (const float*)d_in[4];
  const int* fs = (const int*)d_in[5];
  float* out = (float*)d_out;
  char* ws = (char*)d_ws;

  // workspace layout (bytes)
  unsigned char* XN8  = (unsigned char*)(ws + 0);         // 4096*2048 = 8 MiB
  unsigned char* XBT8 = (unsigned char*)(ws + 8388608);   // 2048*4096 = 8 MiB
  unsigned char* P8   = (unsigned char*)(ws + 16777216);  // 4096*4096 = 16 MiB
  float* R  = (float*)(ws + 33554432);                    // 4096*2048*4 = 32 MiB
  float* LR = (float*)(ws + 67108864);                    // 4096*4
  float* CT = (float*)(ws + 67108864 + 16384);            // 4096*4
  int* MC   = (int*)(ws + 67108864 + 32768);              // 4096*4

  ln_kernel<<<NB, 256, 0, stream>>>(x, y, c, fs, XN8, LR, CT, MC);
  transpose_kernel<<<dim3(64, 32), 256, 0, stream>>>(x, XBT8);
  gemm_sim_kernel<<<528, 256, 0, stream>>>(XN8, P8, LR, MC);
  gemm_recon_kernel<<<dim3(32, 32), 256, 0, stream>>>(P8, XBT8, x, LR, CT, R);
  mix_kernel<<<NB, 256, 0, stream>>>(R, alpha, beta, y, out);
}

// Round 4
// 191.036 us; speedup vs baseline: 1.5971x; 1.1294x over previous
//
#include <hip/hip_runtime.h>
#include <cstdint>
#include <cstddef>

typedef float floatx4 __attribute__((ext_vector_type(4)));
typedef int intx8 __attribute__((ext_vector_type(8)));

#define NB 4096   // batch
#define ND 2048   // feature dim
#define NCLS 64   // classes
#define TSTRIDE 144  // epilogue LDS row stride (bytes), 16B-aligned

// ---------------------------------------------------------------- staging ---
__device__ __forceinline__ void stage16(const void* g, void* l) {
  // async global -> LDS, 16B per lane, LDS dest = wave-uniform base + lane*16
  __builtin_amdgcn_global_load_lds(
      (__attribute__((address_space(1))) unsigned int*)g,
      (__attribute__((address_space(3))) unsigned int*)l, 16, 0, 0);
}

// fp8 e4m3 (OCP) converts, RNE via V_CVT_PK_FP8_F32
__device__ __forceinline__ unsigned char fp8x1(float f) {
  return (unsigned char)(__builtin_amdgcn_cvt_pk_fp8_f32(f, f, 0, false) & 0xFF);
}
__device__ __forceinline__ int fp8x4(float f0, float f1, float f2, float f3) {
  int d = __builtin_amdgcn_cvt_pk_fp8_f32(f0, f1, 0, false);
  return __builtin_amdgcn_cvt_pk_fp8_f32(f2, f3, d, true);
}

// stage one K=128 step of A(128 rows) and B(128 rows) into As/Bs (16 KB each).
// LDS rows of 128 B (8 x 16B chunks), chunk XOR-swizzled by (row&7).
__device__ __forceinline__ void stage_step(const unsigned char* __restrict__ A,
                                           const unsigned char* __restrict__ B,
                                           int K, int m0, int n0, int k0,
                                           unsigned char* As,
                                           unsigned char* Bs) {
  const int t = threadIdx.x;
  const int w = t >> 6, lane = t & 63;
#pragma unroll
  for (int q = 0; q < 4; ++q) {
    const int slot = w * 256 + q * 64 + lane;
    const int row = slot >> 3;
    const int cc = (slot & 7) ^ (row & 7);  // swizzled global chunk
    stage16(A + (size_t)(m0 + row) * K + (k0 + cc * 16),
            As + (w * 256 + q * 64) * 16);
  }
#pragma unroll
  for (int q = 0; q < 4; ++q) {
    const int slot = w * 256 + q * 64 + lane;
    const int row = slot >> 3;
    const int cc = (slot & 7) ^ (row & 7);
    stage16(B + (size_t)(n0 + row) * K + (k0 + cc * 16),
            Bs + (w * 256 + q * 64) * 16);
  }
}

// ------------------------------------------------------------- GEMM core ----
// C[128][128] = A[128][K] * B[128][K]^T, fp8 inputs, fp32 accum via
// mfma_scale 16x16x128 (scales = 1.0 -> byte 127).
// Double-buffered K-loop, ONE barrier per iteration: prefetch k+1 issued
// right after the barrier, flies while k's ds_read+MFMA run; the vmcnt(0)
// drain at the next barrier then has ~0 residual latency.
__device__ __forceinline__ void gemm_core8(const unsigned char* __restrict__ A,
                                           const unsigned char* __restrict__ B,
                                           int K, int m0, int n0,
                                           unsigned char* As0, unsigned char* Bs0,
                                           unsigned char* As1, unsigned char* Bs1,
                                           floatx4 acc[4][4]) {
  const int t = threadIdx.x;
  const int w = t >> 6;
  const int lane = t & 63;
  const int wm = w >> 1, wn = w & 1;
  const int lm = lane & 15, quad = lane >> 4;
  const int nk = K >> 7;

  stage_step(A, B, K, m0, n0, 0, As0, Bs0);

  for (int k = 0; k < nk; ++k) {
    __syncthreads();  // drains vmcnt(0): buf[k&1] staged; prior reads done
    if (k + 1 < nk)
      stage_step(A, B, K, m0, n0, (k + 1) << 7, (k & 1) ? As0 : As1,
                 (k & 1) ? Bs0 : Bs1);
    unsigned char* Ac = (k & 1) ? As1 : As0;
    unsigned char* Bc = (k & 1) ? Bs1 : Bs0;

    intx8 af[4], bfr[4];
#pragma unroll
    for (int i = 0; i < 4; ++i) {
      const int row = wm * 64 + i * 16 + lm;
      const int c0 = (quad * 2) ^ (row & 7);
      const int4 lo = *(const int4*)(Ac + row * 128 + c0 * 16);
      const int4 hi = *(const int4*)(Ac + row * 128 + (c0 ^ 1) * 16);
      af[i][0] = lo.x; af[i][1] = lo.y; af[i][2] = lo.z; af[i][3] = lo.w;
      af[i][4] = hi.x; af[i][5] = hi.y; af[i][6] = hi.z; af[i][7] = hi.w;
    }
#pragma unroll
    for (int i = 0; i < 4; ++i) {
      const int row = wn * 64 + i * 16 + lm;
      const int c0 = (quad * 2) ^ (row & 7);
      const int4 lo = *(const int4*)(Bc + row * 128 + c0 * 16);
      const int4 hi = *(const int4*)(Bc + row * 128 + (c0 ^ 1) * 16);
      bfr[i][0] = lo.x; bfr[i][1] = lo.y; bfr[i][2] = lo.z; bfr[i][3] = lo.w;
      bfr[i][4] = hi.x; bfr[i][5] = hi.y; bfr[i][6] = hi.z; bfr[i][7] = hi.w;
    }
#pragma unroll
    for (int mi = 0; mi < 4; ++mi)
#pragma unroll
      for (int ni = 0; ni < 4; ++ni)
        acc[mi][ni] = __builtin_amdgcn_mfma_scale_f32_16x16x128_f8f6f4(
            af[mi], bfr[ni], acc[mi][ni], 0, 0, 0, 127, 0, 127);
  }
}

// ---------------------------------------------------------------- kernels ---

// LayerNorm: x(fp32) -> XN8 = fp8(x_norm * 32)  (x_norm scaled by 1/sqrt(D));
// the *32 avoids e4m3 subnormal squash; GEMM1 divides acc by 1024.
__global__ __launch_bounds__(256) void ln_kernel(
    const float* __restrict__ x, const int* __restrict__ y,
    const float* __restrict__ c, const int* __restrict__ fs,
    unsigned char* __restrict__ XN8, float* __restrict__ lrow,
    float* __restrict__ contrib, int* __restrict__ maskcol) {
  const int row = blockIdx.x, t = threadIdx.x;
  const float4* xr = (const float4*)(x + (size_t)row * ND);
  float4 v0 = xr[t], v1 = xr[t + 256];
  float s = v0.x + v0.y + v0.z + v0.w + v1.x + v1.y + v1.z + v1.w;
  float q = v0.x * v0.x + v0.y * v0.y + v0.z * v0.z + v0.w * v0.w +
            v1.x * v1.x + v1.y * v1.y + v1.z * v1.z + v1.w * v1.w;
#pragma unroll
  for (int o = 32; o > 0; o >>= 1) {
    s += __shfl_down(s, o);
    q += __shfl_down(q, o);
  }
  __shared__ float ss[4], qq[4];
  const int w = t >> 6;
  if ((t & 63) == 0) { ss[w] = s; qq[w] = q; }
  __syncthreads();
  s = ss[0] + ss[1] + ss[2] + ss[3];
  q = qq[0] + qq[1] + qq[2] + qq[3];
  const float mu = s * (1.0f / ND);
  const float var = q * (1.0f / ND) - mu * mu;
  const float sc =
      rsqrtf(var + 1e-5f) * 0.02209708691207961f * 32.0f;  // /sqrt(2048)*32

  int* orow = (int*)(XN8 + (size_t)row * ND);
  orow[t] = fp8x4((v0.x - mu) * sc, (v0.y - mu) * sc, (v0.z - mu) * sc,
                  (v0.w - mu) * sc);
  orow[256 + t] = fp8x4((v1.x - mu) * sc, (v1.y - mu) * sc, (v1.z - mu) * sc,
                        (v1.w - mu) * sc);

  if (t == 0) {
    lrow[row] = 0.0f;
    const int yi = y[row];
    contrib[row] = c[yi];
    maskcol[row] = fs[yi];
  }
}

// Transpose x (NB x ND fp32) -> XBT8 (ND x NB fp8)
__global__ __launch_bounds__(256) void transpose_kernel(
    const float* __restrict__ x, unsigned char* __restrict__ XBT8) {
  __shared__ float tile[64][65];
  const int rb = blockIdx.x;  // batch tile (0..63)
  const int cb = blockIdx.y;  // feature tile (0..31)
  const int t = threadIdx.x;
  const int tx = t & 63, ty = t >> 6;
#pragma unroll
  for (int rr = ty; rr < 64; rr += 4)
    tile[rr][tx] = x[(size_t)(rb * 64 + rr) * ND + cb * 64 + tx];
  __syncthreads();
  const int ro = t >> 2;  // out row within feature tile
  const int co = t & 3;   // 16-byte chunk within batch tile
  int4 v;
  {
    const int j = co * 16;
    v.x = fp8x4(tile[j + 0][ro], tile[j + 1][ro], tile[j + 2][ro], tile[j + 3][ro]);
    v.y = fp8x4(tile[j + 4][ro], tile[j + 5][ro], tile[j + 6][ro], tile[j + 7][ro]);
    v.z = fp8x4(tile[j + 8][ro], tile[j + 9][ro], tile[j + 10][ro], tile[j + 11][ro]);
    v.w = fp8x4(tile[j + 12][ro], tile[j + 13][ro], tile[j + 14][ro], tile[j + 15][ro]);
  }
  *(int4*)(XBT8 + (size_t)(cb * 64 + ro) * NB + rb * 64 + co * 16) = v;
}

// GEMM1 (triangular): for block (bi<=bj), acc = 1024*sim; e = exp(acc/1024);
// write Pn tile (bi,bj) fp8 w/ col mask of Bj and Pt tile (bj,bi) w/ col mask
// of Bi; accumulate row sums of unquantized e.
__global__ __launch_bounds__(256) void gemm_sim_kernel(
    const unsigned char* __restrict__ XN8, unsigned char* __restrict__ P8,
    float* __restrict__ lrow, const int* __restrict__ maskcol) {
  __shared__ unsigned char smem[65536];
  unsigned char* As0 = smem;
  unsigned char* Bs0 = smem + 16384;
  unsigned char* As1 = smem + 32768;
  unsigned char* Bs1 = smem + 49152;

  // triangular decode: b = bj*(bj+1)/2 + bi, bi <= bj
  const int b = blockIdx.x;
  int bj = (int)((sqrtf(8.0f * (float)b + 1.0f) - 1.0f) * 0.5f);
  while ((bj + 1) * (bj + 2) / 2 <= b) ++bj;
  while (bj * (bj + 1) / 2 > b) --bj;
  const int bi = b - bj * (bj + 1) / 2;
  const int m0 = bi * 128, n0 = bj * 128;

  floatx4 acc[4][4];
#pragma unroll
  for (int i = 0; i < 4; ++i)
#pragma unroll
    for (int j = 0; j < 4; ++j) acc[i][j] = 0.0f;

  gemm_core8(XN8, XN8, ND, m0, n0, As0, Bs0, As1, Bs1, acc);

  const int t = threadIdx.x, w = t >> 6, lane = t & 63;
  const int wm = w >> 1, wn = w & 1, lm = lane & 15, quad = lane >> 4;

  int cmj[4];
#pragma unroll
  for (int ni = 0; ni < 4; ++ni) cmj[ni] = maskcol[n0 + wn * 64 + ni * 16 + lm];
  int rmk[4][4];
#pragma unroll
  for (int mi = 0; mi < 4; ++mi)
#pragma unroll
    for (int r = 0; r < 4; ++r)
      rmk[mi][r] = maskcol[m0 + wm * 64 + mi * 16 + quad * 4 + r];

  // exp in place (diag -> 0), Pn row sums
  float rs[4][4];
#pragma unroll
  for (int mi = 0; mi < 4; ++mi)
#pragma unroll
    for (int r = 0; r < 4; ++r) rs[mi][r] = 0.0f;

#pragma unroll
  for (int ni = 0; ni < 4; ++ni) {
    const int gcol = n0 + wn * 64 + ni * 16 + lm;
#pragma unroll
    for (int mi = 0; mi < 4; ++mi) {
#pragma unroll
      for (int r = 0; r < 4; ++r) {
        const int grow = m0 + wm * 64 + mi * 16 + quad * 4 + r;
        float e = (grow == gcol) ? 0.0f
                                 : __expf(acc[mi][ni][r] * 0.0009765625f);
        acc[mi][ni][r] = e;
        rs[mi][r] += cmj[ni] ? 0.0f : e;
      }
    }
  }
#pragma unroll
  for (int mi = 0; mi < 4; ++mi)
#pragma unroll
    for (int r = 0; r < 4; ++r) {
      float vsum = rs[mi][r];
      vsum += __shfl_xor(vsum, 1);
      vsum += __shfl_xor(vsum, 2);
      vsum += __shfl_xor(vsum, 4);
      vsum += __shfl_xor(vsum, 8);
      if (lm == 0)
        atomicAdd(&lrow[m0 + wm * 64 + mi * 16 + quad * 4 + r], vsum);
    }

  // ---- Pn tile -> LDS (byte scatter) -> coalesced b128 store at (bi,bj)
  __syncthreads();  // core's K-loop ended without a barrier; LDS now reusable
#pragma unroll
  for (int ni = 0; ni < 4; ++ni) {
    const int col = wn * 64 + ni * 16 + lm;
#pragma unroll
    for (int mi = 0; mi < 4; ++mi)
#pragma unroll
      for (int r = 0; r < 4; ++r) {
        const int row = wm * 64 + mi * 16 + quad * 4 + r;
        smem[row * TSTRIDE + col] = fp8x1(cmj[ni] ? 0.0f : acc[mi][ni][r]);
      }
  }
  __syncthreads();
#pragma unroll
  for (int it = 0; it < 4; ++it) {
    const int row = it * 32 + (t >> 3), ch = t & 7;
    int4 v = *(const int4*)(smem + row * TSTRIDE + ch * 16);
    *(int4*)(P8 + (size_t)(m0 + row) * NB + n0 + ch * 16) = v;
  }

  if (bi != bj) {
    __syncthreads();
    // ---- Pt tile: in-lane dword pack (4 rows = 4 consecutive Pt cols)
#pragma unroll
    for (int ni = 0; ni < 4; ++ni) {
      const int tc = wn * 64 + ni * 16 + lm;  // Pt row = original col
      float cs = 0.0f;
#pragma unroll
      for (int mi = 0; mi < 4; ++mi) {
        float g0 = rmk[mi][0] ? 0.0f : acc[mi][ni][0];
        float g1 = rmk[mi][1] ? 0.0f : acc[mi][ni][1];
        float g2 = rmk[mi][2] ? 0.0f : acc[mi][ni][2];
        float g3 = rmk[mi][3] ? 0.0f : acc[mi][ni][3];
        cs += g0 + g1 + g2 + g3;
        *(int*)(smem + tc * TSTRIDE + wm * 64 + mi * 16 + quad * 4) =
            fp8x4(g0, g1, g2, g3);
      }
      cs += __shfl_xor(cs, 16);
      cs += __shfl_xor(cs, 32);
      if (quad == 0) atomicAdd(&lrow[n0 + tc], cs);
    }
    __syncthreads();
#pragma unroll
    for (int it = 0; it < 4; ++it) {
      const int row = it * 32 + (t >> 3), ch = t & 7;
      int4 v = *(const int4*)(smem + row * TSTRIDE + ch * 16);
      *(int4*)(P8 + (size_t)(n0 + row) * NB + m0 + ch * 16) = v;
    }
  }
}

// GEMM2: R = (P8 @ XBT8^T)/l * contrib + x*(1-contrib). 128x128 tiles,
// grid 512 = exactly 2 blocks/CU; dbuf K-loop hides load latency.
__global__ __launch_bounds__(256) void gemm_recon_kernel(
    const unsigned char* __restrict__ P8, const unsigned char* __restrict__ XBT8,
    const float* __restrict__ x, const float* __restrict__ lrow,
    const float* __restrict__ contrib, float* __restrict__ R) {
  __shared__ unsigned char smem[65536];
  unsigned char* As0 = smem;
  unsigned char* Bs0 = smem + 16384;
  unsigned char* As1 = smem + 32768;
  unsigned char* Bs1 = smem + 49152;
  const int m0 = blockIdx.y * 128, n0 = blockIdx.x * 128;
  floatx4 acc[4][4];
#pragma unroll
  for (int i = 0; i < 4; ++i)
#pragma unroll
    for (int j = 0; j < 4; ++j) acc[i][j] = 0.0f;

  gemm_core8(P8, XBT8, NB, m0, n0, As0, Bs0, As1, Bs1, acc);

  const int t = threadIdx.x, w = t >> 6, lane = t & 63;
  const int wm = w >> 1, wn = w & 1, lm = lane & 15, quad = lane >> 4;
#pragma unroll
  for (int mi = 0; mi < 4; ++mi) {
#pragma unroll
    for (int r = 0; r < 4; ++r) {
      const int grow = m0 + wm * 64 + mi * 16 + quad * 4 + r;
      const float inv = 1.0f / lrow[grow];
      const float ci = contrib[grow];
#pragma unroll
      for (int ni = 0; ni < 4; ++ni) {
        const int gcol = n0 + wn * 64 + ni * 16 + lm;
        const float rec = acc[mi][ni][r] * inv;
        const float xv = x[(size_t)grow * ND + gcol];
        R[(size_t)grow * ND + gcol] = rec * ci + xv * (1.0f - ci);
      }
    }
  }
}

// Mix: x_mix = a*R[i] + (1-a)*R[beta[i]]; y_mix from one-hots.
__global__ __launch_bounds__(256) void mix_kernel(
    const float* __restrict__ R, const float* __restrict__ alpha,
    const int* __restrict__ beta_idx, const int* __restrict__ y,
    float* __restrict__ out) {
  const int i = blockIdx.x, t = threadIdx.x;
  const float a = alpha[i];
  const int bi = beta_idx[i];
  const float4* Ri = (const float4*)(R + (size_t)i * ND);
  const float4* Rb = (const float4*)(R + (size_t)bi * ND);
  float4* o = (float4*)(out + (size_t)i * ND);
  const float b = 1.0f - a;
#pragma unroll
  for (int j = 0; j < 2; ++j) {
    const int idx = t + j * 256;
    float4 r = Ri[idx], g = Rb[idx], ov;
    ov.x = a * r.x + b * g.x;
    ov.y = a * r.y + b * g.y;
    ov.z = a * r.z + b * g.z;
    ov.w = a * r.w + b * g.w;
    o[idx] = ov;
  }
  if (t < NCLS) {
    const int yi = y[i], yb = y[bi];
    const float v = a * (t == yi ? 1.0f : 0.0f) + b * (t == yb ? 1.0f : 0.0f);
    out[(size_t)NB * ND + (size_t)i * NCLS + t] = v;
  }
}

// ------------------------------------------------------------------ launch --
extern "C" void kernel_launch(void* const* d_in, const int* in_sizes, int n_in,
                              void* d_out, int out_size, void* d_ws,
                              size_t ws_size, hipStream_t stream) {
  const float* x = (const float*)d_in[0];
  const int* y = (const int*)d_in[1];
  const float* alpha = (const float*)d_in[2];
  const int* beta = (const int*)d_in[3];
  const float* c = (const float*)d_in[4];
  const int* fs = (const int*)d_in[5];
  float* out = (float*)d_out;
  char* ws = (char*)d_ws;

  // workspace layout (bytes)
  unsigned char* XN8  = (unsigned char*)(ws + 0);         // 4096*2048 = 8 MiB
  unsigned char* XBT8 = (unsigned char*)(ws + 8388608);   // 2048*4096 = 8 MiB
  unsigned char* P8   = (unsigned char*)(ws + 16777216);  // 4096*4096 = 16 MiB
  float* R  = (float*)(ws + 33554432);                    // 4096*2048*4 = 32 MiB
  float* LR = (float*)(ws + 67108864);                    // 4096*4
  float* CT = (float*)(ws + 67108864 + 16384);            // 4096*4
  int* MC   = (int*)(ws + 67108864 + 32768);              // 4096*4

  ln_kernel<<<NB, 256, 0, stream>>>(x, y, c, fs, XN8, LR, CT, MC);
  transpose_kernel<<<dim3(64, 32), 256, 0, stream>>>(x, XBT8);
  gemm_sim_kernel<<<528, 256, 0, stream>>>(XN8, P8, LR, MC);
  gemm_recon_kernel<<<dim3(16, 32), 256, 0, stream>>>(P8, XBT8, x, LR, CT, R);
  mix_kernel<<<NB, 256, 0, stream>>>(R, alpha, beta, y, out);
}

// Round 5
// 179.070 us; speedup vs baseline: 1.7038x; 1.0668x over previous
//
#include <hip/hip_runtime.h>
#include <cstdint>
#include <cstddef>

typedef __bf16 bf16;
typedef __bf16 bf16x8 __attribute__((ext_vector_type(8)));
typedef float floatx4 __attribute__((ext_vector_type(4)));
typedef int intx8 __attribute__((ext_vector_type(8)));

#define NB 4096   // batch
#define ND 2048   // feature dim
#define NCLS 64   // classes
#define TSTRIDE 144  // sim epilogue LDS row stride (bytes), 16B-aligned
#define OS 136       // recon epilogue LDS row stride (bf16 elems, 272 B)

// ---------------------------------------------------------------- staging ---
__device__ __forceinline__ void stage16(const void* g, void* l) {
  // async global -> LDS, 16B per lane, LDS dest = wave-uniform base + lane*16
  __builtin_amdgcn_global_load_lds(
      (__attribute__((address_space(1))) unsigned int*)g,
      (__attribute__((address_space(3))) unsigned int*)l, 16, 0, 0);
}

// fp8 e4m3 (OCP) converts, RNE via V_CVT_PK_FP8_F32
__device__ __forceinline__ unsigned char fp8x1(float f) {
  return (unsigned char)(__builtin_amdgcn_cvt_pk_fp8_f32(f, f, 0, false) & 0xFF);
}
__device__ __forceinline__ int fp8x4(float f0, float f1, float f2, float f3) {
  int d = __builtin_amdgcn_cvt_pk_fp8_f32(f0, f1, 0, false);
  return __builtin_amdgcn_cvt_pk_fp8_f32(f2, f3, d, true);
}

// stage one K=128 step of A(128 rows) and B(128 rows) into As/Bs (16 KB each).
// LDS rows of 128 B (8 x 16B chunks), chunk XOR-swizzled by (row&7).
__device__ __forceinline__ void stage_step(const unsigned char* __restrict__ A,
                                           const unsigned char* __restrict__ B,
                                           int K, int m0, int n0, int k0,
                                           unsigned char* As,
                                           unsigned char* Bs) {
  const int t = threadIdx.x;
  const int w = t >> 6, lane = t & 63;
#pragma unroll
  for (int q = 0; q < 4; ++q) {
    const int slot = w * 256 + q * 64 + lane;
    const int row = slot >> 3;
    const int cc = (slot & 7) ^ (row & 7);  // swizzled global chunk
    stage16(A + (size_t)(m0 + row) * K + (k0 + cc * 16),
            As + (w * 256 + q * 64) * 16);
  }
#pragma unroll
  for (int q = 0; q < 4; ++q) {
    const int slot = w * 256 + q * 64 + lane;
    const int row = slot >> 3;
    const int cc = (slot & 7) ^ (row & 7);
    stage16(B + (size_t)(n0 + row) * K + (k0 + cc * 16),
            Bs + (w * 256 + q * 64) * 16);
  }
}

// ------------------------------------------------------------- GEMM core ----
// C[128][128] = A[128][K] * B[128][K]^T, fp8 inputs, fp32 accum via
// mfma_scale 16x16x128 (scales = 1.0 -> byte 127).
// Double-buffered K-loop, ONE barrier per iteration.
__device__ __forceinline__ void gemm_core8(const unsigned char* __restrict__ A,
                                           const unsigned char* __restrict__ B,
                                           int K, int m0, int n0,
                                           unsigned char* As0, unsigned char* Bs0,
                                           unsigned char* As1, unsigned char* Bs1,
                                           floatx4 acc[4][4]) {
  const int t = threadIdx.x;
  const int w = t >> 6;
  const int lane = t & 63;
  const int wm = w >> 1, wn = w & 1;
  const int lm = lane & 15, quad = lane >> 4;
  const int nk = K >> 7;

  stage_step(A, B, K, m0, n0, 0, As0, Bs0);

  for (int k = 0; k < nk; ++k) {
    __syncthreads();  // drains vmcnt(0): buf[k&1] staged; prior reads done
    if (k + 1 < nk)
      stage_step(A, B, K, m0, n0, (k + 1) << 7, (k & 1) ? As0 : As1,
                 (k & 1) ? Bs0 : Bs1);
    unsigned char* Ac = (k & 1) ? As1 : As0;
    unsigned char* Bc = (k & 1) ? Bs1 : Bs0;

    intx8 af[4], bfr[4];
#pragma unroll
    for (int i = 0; i < 4; ++i) {
      const int row = wm * 64 + i * 16 + lm;
      const int c0 = (quad * 2) ^ (row & 7);
      const int4 lo = *(const int4*)(Ac + row * 128 + c0 * 16);
      const int4 hi = *(const int4*)(Ac + row * 128 + (c0 ^ 1) * 16);
      af[i][0] = lo.x; af[i][1] = lo.y; af[i][2] = lo.z; af[i][3] = lo.w;
      af[i][4] = hi.x; af[i][5] = hi.y; af[i][6] = hi.z; af[i][7] = hi.w;
    }
#pragma unroll
    for (int i = 0; i < 4; ++i) {
      const int row = wn * 64 + i * 16 + lm;
      const int c0 = (quad * 2) ^ (row & 7);
      const int4 lo = *(const int4*)(Bc + row * 128 + c0 * 16);
      const int4 hi = *(const int4*)(Bc + row * 128 + (c0 ^ 1) * 16);
      bfr[i][0] = lo.x; bfr[i][1] = lo.y; bfr[i][2] = lo.z; bfr[i][3] = lo.w;
      bfr[i][4] = hi.x; bfr[i][5] = hi.y; bfr[i][6] = hi.z; bfr[i][7] = hi.w;
    }
#pragma unroll
    for (int mi = 0; mi < 4; ++mi)
#pragma unroll
      for (int ni = 0; ni < 4; ++ni)
        acc[mi][ni] = __builtin_amdgcn_mfma_scale_f32_16x16x128_f8f6f4(
            af[mi], bfr[ni], acc[mi][ni], 0, 0, 0, 127, 0, 127);
  }
}

// ---------------------------------------------------------------- kernels ---

// Fused prep: blocks 0..NB-1 do LayerNorm (x -> XN8 = fp8(x_norm*32), plus
// lrow=0, contrib, maskcol); blocks NB.. do 64x64 transpose x -> XBT8 (fp8).
__global__ __launch_bounds__(256) void prep_kernel(
    const float* __restrict__ x, const int* __restrict__ y,
    const float* __restrict__ c, const int* __restrict__ fs,
    unsigned char* __restrict__ XN8, unsigned char* __restrict__ XBT8,
    float* __restrict__ lrow, float* __restrict__ contrib,
    int* __restrict__ maskcol) {
  __shared__ float tile[64][65];
  const int t = threadIdx.x;

  if (blockIdx.x < NB) {
    // ---------------- LayerNorm branch
    const int row = blockIdx.x;
    const float4* xr = (const float4*)(x + (size_t)row * ND);
    float4 v0 = xr[t], v1 = xr[t + 256];
    float s = v0.x + v0.y + v0.z + v0.w + v1.x + v1.y + v1.z + v1.w;
    float q = v0.x * v0.x + v0.y * v0.y + v0.z * v0.z + v0.w * v0.w +
              v1.x * v1.x + v1.y * v1.y + v1.z * v1.z + v1.w * v1.w;
#pragma unroll
    for (int o = 32; o > 0; o >>= 1) {
      s += __shfl_down(s, o);
      q += __shfl_down(q, o);
    }
    const int w = t >> 6;
    if ((t & 63) == 0) { tile[0][w] = s; tile[1][w] = q; }
    __syncthreads();
    s = tile[0][0] + tile[0][1] + tile[0][2] + tile[0][3];
    q = tile[1][0] + tile[1][1] + tile[1][2] + tile[1][3];
    const float mu = s * (1.0f / ND);
    const float var = q * (1.0f / ND) - mu * mu;
    const float sc =
        rsqrtf(var + 1e-5f) * 0.02209708691207961f * 32.0f;  // /sqrt(2048)*32

    int* orow = (int*)(XN8 + (size_t)row * ND);
    orow[t] = fp8x4((v0.x - mu) * sc, (v0.y - mu) * sc, (v0.z - mu) * sc,
                    (v0.w - mu) * sc);
    orow[256 + t] = fp8x4((v1.x - mu) * sc, (v1.y - mu) * sc, (v1.z - mu) * sc,
                          (v1.w - mu) * sc);

    if (t == 0) {
      lrow[row] = 0.0f;
      const int yi = y[row];
      contrib[row] = c[yi];
      maskcol[row] = fs[yi];
    }
  } else {
    // ---------------- transpose branch: x (NB x ND fp32) -> XBT8 (ND x NB)
    const int b2 = blockIdx.x - NB;
    const int rb = b2 & 63;  // batch tile (0..63)
    const int cb = b2 >> 6;  // feature tile (0..31)
    const int tx = t & 63, ty = t >> 6;
#pragma unroll
    for (int rr = ty; rr < 64; rr += 4)
      tile[rr][tx] = x[(size_t)(rb * 64 + rr) * ND + cb * 64 + tx];
    __syncthreads();
    const int ro = t >> 2;  // out row within feature tile
    const int co = t & 3;   // 16-byte chunk within batch tile
    int4 v;
    {
      const int j = co * 16;
      v.x = fp8x4(tile[j + 0][ro], tile[j + 1][ro], tile[j + 2][ro], tile[j + 3][ro]);
      v.y = fp8x4(tile[j + 4][ro], tile[j + 5][ro], tile[j + 6][ro], tile[j + 7][ro]);
      v.z = fp8x4(tile[j + 8][ro], tile[j + 9][ro], tile[j + 10][ro], tile[j + 11][ro]);
      v.w = fp8x4(tile[j + 12][ro], tile[j + 13][ro], tile[j + 14][ro], tile[j + 15][ro]);
    }
    *(int4*)(XBT8 + (size_t)(cb * 64 + ro) * NB + rb * 64 + co * 16) = v;
  }
}

// GEMM1 (triangular): for block (bi<=bj), acc = 1024*sim; e = exp(acc/1024);
// write Pn tile (bi,bj) fp8 w/ col mask of Bj and Pt tile (bj,bi) w/ col mask
// of Bi; accumulate row sums of unquantized e.
__global__ __launch_bounds__(256) void gemm_sim_kernel(
    const unsigned char* __restrict__ XN8, unsigned char* __restrict__ P8,
    float* __restrict__ lrow, const int* __restrict__ maskcol) {
  __shared__ unsigned char smem[65536];
  unsigned char* As0 = smem;
  unsigned char* Bs0 = smem + 16384;
  unsigned char* As1 = smem + 32768;
  unsigned char* Bs1 = smem + 49152;

  // triangular decode: b = bj*(bj+1)/2 + bi, bi <= bj
  const int b = blockIdx.x;
  int bj = (int)((sqrtf(8.0f * (float)b + 1.0f) - 1.0f) * 0.5f);
  while ((bj + 1) * (bj + 2) / 2 <= b) ++bj;
  while (bj * (bj + 1) / 2 > b) --bj;
  const int bi = b - bj * (bj + 1) / 2;
  const int m0 = bi * 128, n0 = bj * 128;

  floatx4 acc[4][4];
#pragma unroll
  for (int i = 0; i < 4; ++i)
#pragma unroll
    for (int j = 0; j < 4; ++j) acc[i][j] = 0.0f;

  gemm_core8(XN8, XN8, ND, m0, n0, As0, Bs0, As1, Bs1, acc);

  const int t = threadIdx.x, w = t >> 6, lane = t & 63;
  const int wm = w >> 1, wn = w & 1, lm = lane & 15, quad = lane >> 4;

  int cmj[4];
#pragma unroll
  for (int ni = 0; ni < 4; ++ni) cmj[ni] = maskcol[n0 + wn * 64 + ni * 16 + lm];
  int rmk[4][4];
#pragma unroll
  for (int mi = 0; mi < 4; ++mi)
#pragma unroll
    for (int r = 0; r < 4; ++r)
      rmk[mi][r] = maskcol[m0 + wm * 64 + mi * 16 + quad * 4 + r];

  // exp in place (diag -> 0), Pn row sums
  float rs[4][4];
#pragma unroll
  for (int mi = 0; mi < 4; ++mi)
#pragma unroll
    for (int r = 0; r < 4; ++r) rs[mi][r] = 0.0f;

#pragma unroll
  for (int ni = 0; ni < 4; ++ni) {
    const int gcol = n0 + wn * 64 + ni * 16 + lm;
#pragma unroll
    for (int mi = 0; mi < 4; ++mi) {
#pragma unroll
      for (int r = 0; r < 4; ++r) {
        const int grow = m0 + wm * 64 + mi * 16 + quad * 4 + r;
        float e = (grow == gcol) ? 0.0f
                                 : __expf(acc[mi][ni][r] * 0.0009765625f);
        acc[mi][ni][r] = e;
        rs[mi][r] += cmj[ni] ? 0.0f : e;
      }
    }
  }
#pragma unroll
  for (int mi = 0; mi < 4; ++mi)
#pragma unroll
    for (int r = 0; r < 4; ++r) {
      float vsum = rs[mi][r];
      vsum += __shfl_xor(vsum, 1);
      vsum += __shfl_xor(vsum, 2);
      vsum += __shfl_xor(vsum, 4);
      vsum += __shfl_xor(vsum, 8);
      if (lm == 0)
        atomicAdd(&lrow[m0 + wm * 64 + mi * 16 + quad * 4 + r], vsum);
    }

  // ---- Pn tile -> LDS (byte scatter) -> coalesced b128 store at (bi,bj)
  __syncthreads();  // core's K-loop ended without a barrier; LDS now reusable
#pragma unroll
  for (int ni = 0; ni < 4; ++ni) {
    const int col = wn * 64 + ni * 16 + lm;
#pragma unroll
    for (int mi = 0; mi < 4; ++mi)
#pragma unroll
      for (int r = 0; r < 4; ++r) {
        const int row = wm * 64 + mi * 16 + quad * 4 + r;
        smem[row * TSTRIDE + col] = fp8x1(cmj[ni] ? 0.0f : acc[mi][ni][r]);
      }
  }
  __syncthreads();
#pragma unroll
  for (int it = 0; it < 4; ++it) {
    const int row = it * 32 + (t >> 3), ch = t & 7;
    int4 v = *(const int4*)(smem + row * TSTRIDE + ch * 16);
    *(int4*)(P8 + (size_t)(m0 + row) * NB + n0 + ch * 16) = v;
  }

  if (bi != bj) {
    __syncthreads();
    // ---- Pt tile: in-lane dword pack (4 rows = 4 consecutive Pt cols)
#pragma unroll
    for (int ni = 0; ni < 4; ++ni) {
      const int tc = wn * 64 + ni * 16 + lm;  // Pt row = original col
      float cs = 0.0f;
#pragma unroll
      for (int mi = 0; mi < 4; ++mi) {
        float g0 = rmk[mi][0] ? 0.0f : acc[mi][ni][0];
        float g1 = rmk[mi][1] ? 0.0f : acc[mi][ni][1];
        float g2 = rmk[mi][2] ? 0.0f : acc[mi][ni][2];
        float g3 = rmk[mi][3] ? 0.0f : acc[mi][ni][3];
        cs += g0 + g1 + g2 + g3;
        *(int*)(smem + tc * TSTRIDE + wm * 64 + mi * 16 + quad * 4) =
            fp8x4(g0, g1, g2, g3);
      }
      cs += __shfl_xor(cs, 16);
      cs += __shfl_xor(cs, 32);
      if (quad == 0) atomicAdd(&lrow[n0 + tc], cs);
    }
    __syncthreads();
#pragma unroll
    for (int it = 0; it < 4; ++it) {
      const int row = it * 32 + (t >> 3), ch = t & 7;
      int4 v = *(const int4*)(smem + row * TSTRIDE + ch * 16);
      *(int4*)(P8 + (size_t)(n0 + row) * NB + m0 + ch * 16) = v;
    }
  }
}

// GEMM2: R(bf16) = (P8 @ XBT8^T)/l * contrib + x*(1-contrib).
// 1-D grid 512, XCD-swizzled: each XCD owns 2 n-tiles -> its XBT slice
// (1 MB) is L2-resident. Epilogue repacks via LDS for b128 stores.
__global__ __launch_bounds__(256) void gemm_recon_kernel(
    const unsigned char* __restrict__ P8, const unsigned char* __restrict__ XBT8,
    const float* __restrict__ x, const float* __restrict__ lrow,
    const float* __restrict__ contrib, bf16* __restrict__ R) {
  __shared__ unsigned char smem[65536];
  unsigned char* As0 = smem;
  unsigned char* Bs0 = smem + 16384;
  unsigned char* As1 = smem + 32768;
  unsigned char* Bs1 = smem + 49152;

  // XCD swizzle: id%8 = XCD (round-robin dispatch); give each XCD n-tiles
  // {xcd*2, xcd*2+1} so its XBT working set is 1 MB (fits 4 MB XCD L2).
  const int id = blockIdx.x;
  const int xcd = id & 7;
  const int s = id >> 3;
  const int bx = xcd * 2 + (s & 1);
  const int by = s >> 1;
  const int m0 = by * 128, n0 = bx * 128;

  floatx4 acc[4][4];
#pragma unroll
  for (int i = 0; i < 4; ++i)
#pragma unroll
    for (int j = 0; j < 4; ++j) acc[i][j] = 0.0f;

  gemm_core8(P8, XBT8, NB, m0, n0, As0, Bs0, As1, Bs1, acc);

  const int t = threadIdx.x, w = t >> 6, lane = t & 63;
  const int wm = w >> 1, wn = w & 1, lm = lane & 15, quad = lane >> 4;

  __syncthreads();  // waves done reading K-loop buffers; reuse smem
  bf16* osm = (bf16*)smem;
#pragma unroll
  for (int mi = 0; mi < 4; ++mi) {
#pragma unroll
    for (int r = 0; r < 4; ++r) {
      const int lrow_i = wm * 64 + mi * 16 + quad * 4 + r;
      const int grow = m0 + lrow_i;
      const float inv = 1.0f / lrow[grow];
      const float ci = contrib[grow];
#pragma unroll
      for (int ni = 0; ni < 4; ++ni) {
        const int lcol = wn * 64 + ni * 16 + lm;
        const float rec = acc[mi][ni][r] * inv;
        const float xv = x[(size_t)grow * ND + n0 + lcol];
        osm[lrow_i * OS + lcol] = (bf16)(rec * ci + xv * (1.0f - ci));
      }
    }
  }
  __syncthreads();
#pragma unroll
  for (int it = 0; it < 8; ++it) {
    const int row = it * 16 + (t >> 4), ch = t & 15;
    int4 v = *(const int4*)(osm + row * OS + ch * 8);
    *(int4*)(R + (size_t)(m0 + row) * ND + n0 + ch * 8) = v;
  }
}

// Mix: x_mix = a*R[i] + (1-a)*R[beta[i]] (R in bf16); y_mix from one-hots.
__global__ __launch_bounds__(256) void mix_kernel(
    const bf16* __restrict__ R, const float* __restrict__ alpha,
    const int* __restrict__ beta_idx, const int* __restrict__ y,
    float* __restrict__ out) {
  const int i = blockIdx.x, t = threadIdx.x;
  const float a = alpha[i];
  const int bi = beta_idx[i];
  const bf16x8* Ri = (const bf16x8*)(R + (size_t)i * ND);
  const bf16x8* Rb = (const bf16x8*)(R + (size_t)bi * ND);
  const float b = 1.0f - a;
  bf16x8 r = Ri[t], g = Rb[t];
  float4 o0, o1;
  o0.x = a * (float)r[0] + b * (float)g[0];
  o0.y = a * (float)r[1] + b * (float)g[1];
  o0.z = a * (float)r[2] + b * (float)g[2];
  o0.w = a * (float)r[3] + b * (float)g[3];
  o1.x = a * (float)r[4] + b * (float)g[4];
  o1.y = a * (float)r[5] + b * (float)g[5];
  o1.z = a * (float)r[6] + b * (float)g[6];
  o1.w = a * (float)r[7] + b * (float)g[7];
  float4* o = (float4*)(out + (size_t)i * ND + t * 8);
  o[0] = o0;
  o[1] = o1;
  if (t < NCLS) {
    const int yi = y[i], yb = y[bi];
    const float v = a * (t == yi ? 1.0f : 0.0f) + b * (t == yb ? 1.0f : 0.0f);
    out[(size_t)NB * ND + (size_t)i * NCLS + t] = v;
  }
}

// ------------------------------------------------------------------ launch --
extern "C" void kernel_launch(void* const* d_in, const int* in_sizes, int n_in,
                              void* d_out, int out_size, void* d_ws,
                              size_t ws_size, hipStream_t stream) {
  const float* x = (const float*)d_in[0];
  const int* y = (const int*)d_in[1];
  const float* alpha = (const float*)d_in[2];
  const int* beta = (const int*)d_in[3];
  const float* c = (const float*)d_in[4];
  const int* fs = (const int*)d_in[5];
  float* out = (float*)d_out;
  char* ws = (char*)d_ws;

  // workspace layout (bytes)
  unsigned char* XN8  = (unsigned char*)(ws + 0);         // 4096*2048 = 8 MiB
  unsigned char* XBT8 = (unsigned char*)(ws + 8388608);   // 2048*4096 = 8 MiB
  unsigned char* P8   = (unsigned char*)(ws + 16777216);  // 4096*4096 = 16 MiB
  bf16* R   = (bf16*)(ws + 33554432);                     // 4096*2048*2 = 16 MiB
  float* LR = (float*)(ws + 50331648);                    // 4096*4
  float* CT = (float*)(ws + 50331648 + 16384);            // 4096*4
  int* MC   = (int*)(ws + 50331648 + 32768);              // 4096*4

  prep_kernel<<<NB + 2048, 256, 0, stream>>>(x, y, c, fs, XN8, XBT8, LR, CT, MC);
  gemm_sim_kernel<<<528, 256, 0, stream>>>(XN8, P8, LR, MC);
  gemm_recon_kernel<<<512, 256, 0, stream>>>(P8, XBT8, x, LR, CT, R);
  mix_kernel<<<NB, 256, 0, stream>>>(R, alpha, beta, y, out);
}